// Round 5
// baseline (766.035 us; speedup 1.0000x reference)
//
#include <hip/hip_runtime.h>
#include <cstdio>

// ---------------------------------------------------------------------------
// GCN 2-layer forward on MI355X.  Round 5: commuted layer 1 — Â(XW1)=(ÂX)W1.
// Pipeline:
//   1. k_zero/bhist/bscan/partition/bucket: bucketed counting sort by dst
//      -> esrc[], off[], dinv[]   (shared by both aggregations)
//   2. k_castX:  x fp32 -> xh fp16
//   3. k_castW:  W1,W2 -> (Wh,Wl) fp16 splits, TRANSPOSED [N][K] (one launch)
//   4. agg0:  xa = Â xh            (wave/node gather, fp32 acc, fp16 out)
//   5. gemm1: h1r = relu(xa@W1+b1) (2-term split-W MFMA, bias+relu epilogue)
//   6. gemm2: h2  = h1r@W2         (2-term)
//   7. agg2:  out = Â h2 + b2      (fp32 out)
// All GEMMs: A exact fp16, B split fp16 (fp32-equivalent), fp32 accum.
// ---------------------------------------------------------------------------

#define NPB 256        // nodes per bucket (power of 2: bucket = dst >> 8)
#define PCHUNK 8192    // edges per partition block

template <int V> struct vec_t;
template <> struct vec_t<2> {
  typedef float    fv __attribute__((ext_vector_type(2)));
  typedef _Float16 hv __attribute__((ext_vector_type(2)));
};
template <> struct vec_t<4> {
  typedef float    fv __attribute__((ext_vector_type(4)));
  typedef _Float16 hv __attribute__((ext_vector_type(4)));
};
typedef _Float16 half4v __attribute__((ext_vector_type(4)));
typedef _Float16 half8v __attribute__((ext_vector_type(8)));
typedef float    f32x4  __attribute__((ext_vector_type(4)));

__global__ __launch_bounds__(256) void k_zero(int* p, int n) {
  int i = blockIdx.x * 256 + threadIdx.x;
  if (i < n) p[i] = 0;
}

// bucket histogram, LDS-privatized
__global__ __launch_bounds__(256) void k_bhist(const int* __restrict__ dst,
                                               int* __restrict__ bcnt,
                                               int e, int nb) {
  __shared__ int h[512];
  for (int i = threadIdx.x; i < nb; i += 256) h[i] = 0;
  __syncthreads();
  int c0 = blockIdx.x * PCHUNK;
  int c1 = min(c0 + PCHUNK, e);
  for (int i = c0 + threadIdx.x; i < c1; i += 256)
    atomicAdd(&h[dst[i] >> 8], 1);
  __syncthreads();
  for (int i = threadIdx.x; i < nb; i += 256)
    if (h[i]) atomicAdd(&bcnt[i], h[i]);
}

// single-block scan of bucket counts -> bbase[0..nb], gcur init
__global__ __launch_bounds__(512) void k_bscan(const int* __restrict__ bcnt,
                                               int* __restrict__ bbase,
                                               int* __restrict__ gcur, int nb) {
  __shared__ int sm[512];
  int tid = threadIdx.x;
  sm[tid] = (tid < nb) ? bcnt[tid] : 0;
  __syncthreads();
  for (int d = 1; d < 512; d <<= 1) {
    int t = (tid >= d) ? sm[tid - d] : 0;
    __syncthreads();
    sm[tid] += t;
    __syncthreads();
  }
  int ex = (tid == 0) ? 0 : sm[tid - 1];
  if (tid < nb) {
    bbase[tid] = ex;
    gcur[tid] = ex;
  }
  if (tid == nb) bbase[nb] = sm[nb - 1];
}

// bucket partition: contiguous runs of packed (src,dst) per (block,bucket)
__global__ __launch_bounds__(256) void k_partition(const int* __restrict__ src,
                                                   const int* __restrict__ dst,
                                                   int* __restrict__ gcur,
                                                   uint2* __restrict__ tmp,
                                                   int e, int nb) {
  __shared__ int hist[512];
  __shared__ int base[512];
  for (int i = threadIdx.x; i < nb; i += 256) hist[i] = 0;
  __syncthreads();
  int c0 = blockIdx.x * PCHUNK;
  int c1 = min(c0 + PCHUNK, e);
  for (int i = c0 + threadIdx.x; i < c1; i += 256)
    atomicAdd(&hist[dst[i] >> 8], 1);
  __syncthreads();
  for (int i = threadIdx.x; i < nb; i += 256) {
    int c = hist[i];
    base[i] = c ? atomicAdd(&gcur[i], c) : 0;
    hist[i] = 0;  // reuse as local cursor
  }
  __syncthreads();
  for (int i = c0 + threadIdx.x; i < c1; i += 256) {
    int d = dst[i];
    int b = d >> 8;
    int pos = base[b] + atomicAdd(&hist[b], 1);
    uint2 v;
    v.x = (unsigned)src[i];
    v.y = (unsigned)d;
    tmp[pos] = v;
  }
}

// per-bucket sort: produce esrc (sorted by dst), off[], dinv[]
__global__ __launch_bounds__(256) void k_bucket(const uint2* __restrict__ tmp,
                                                const int* __restrict__ bbase,
                                                int* __restrict__ off,
                                                float* __restrict__ dinv,
                                                int* __restrict__ esrc, int n) {
  __shared__ int lcnt[NPB];
  __shared__ int lsum[NPB];
  __shared__ int lcur[NPB];
  const int b = blockIdx.x;
  const int tid = threadIdx.x;
  const int r0 = b << 8;
  const int nn = min(NPB, n - r0);
  const int lo = bbase[b], hi = bbase[b + 1];

  lcnt[tid] = 0;
  __syncthreads();
  for (int i = lo + tid; i < hi; i += 256)
    atomicAdd(&lcnt[tmp[i].y & (NPB - 1)], 1);
  __syncthreads();
  lsum[tid] = lcnt[tid];
  __syncthreads();
  for (int d = 1; d < NPB; d <<= 1) {
    int t = (tid >= d) ? lsum[tid - d] : 0;
    __syncthreads();
    lsum[tid] += t;
    __syncthreads();
  }
  int ex = (tid == 0) ? 0 : lsum[tid - 1];
  if (tid < nn) {
    off[r0 + tid] = lo + ex;
    dinv[r0 + tid] = rsqrtf((float)(lcnt[tid] + 1));  // +1 self loop
    lcur[tid] = lo + ex;
  }
  if (r0 + nn == n && tid == 0) off[n] = hi;
  __syncthreads();
  for (int i = lo + tid; i < hi; i += 256) {
    uint2 t2 = tmp[i];
    int pos = atomicAdd(&lcur[t2.y & (NPB - 1)], 1);
    esrc[pos] = (int)t2.x;
  }
}

// ---------------------------------------------------------------------------
// x fp32 -> fp16 (vectorized stream cast)
// ---------------------------------------------------------------------------
__global__ __launch_bounds__(256) void k_castX(const float* __restrict__ x,
                                               _Float16* __restrict__ xh,
                                               int n4) {
  int i = blockIdx.x * 256 + threadIdx.x;
  if (i >= n4) return;
  f32x4 v = *(const f32x4*)(x + (size_t)i * 4);
  half4v h;
#pragma unroll
  for (int j = 0; j < 4; ++j) h[j] = (_Float16)v[j];
  *(half4v*)(xh + (size_t)i * 4) = h;
}

// ---------------------------------------------------------------------------
// W1,W2 -> split fp16, transposed [N][K] (single launch for both weights)
// ---------------------------------------------------------------------------
__global__ __launch_bounds__(256) void k_castW(
    const float* __restrict__ W1, const float* __restrict__ W2,
    _Float16* __restrict__ w1h, _Float16* __restrict__ w1l,
    _Float16* __restrict__ w2h, _Float16* __restrict__ w2l) {
  int i = blockIdx.x * 256 + threadIdx.x;
  if (i < 256 * 256) {
    int n = i & 255, k = i >> 8;         // W1 is [256][256]
    float v = W1[i];
    _Float16 h = (_Float16)v;
    w1h[(size_t)n * 256 + k] = h;
    w1l[(size_t)n * 256 + k] = (_Float16)(v - (float)h);
  } else if (i < 256 * 256 + 256 * 128) {
    int j = i - 256 * 256;               // W2 is [256][128]
    int n = j & 127, k = j >> 7;
    float v = W2[j];
    _Float16 h = (_Float16)v;
    w2h[(size_t)n * 256 + k] = h;
    w2l[(size_t)n * 256 + k] = (_Float16)(v - (float)h);
  }
}

// ---------------------------------------------------------------------------
// MFMA GEMM: C[M,N] = fp16(A[M,K] @ B[K,N]) [+bias, relu], fp32 accumulate.
// A exact fp16; B split: acc += A*Bh + A*Bl  (fp32-equivalent).
// Tile: 128x128, BK=32, 4 waves, each wave 64x64 = 4x4 frags of 16x16x32.
// A staged in LDS (stride 40 halves); B frags direct from global [N][K]
// (L2-resident).  Layouts (m89/m91-verified): A[m=lane&15][k=quad*8+j],
// B[k=quad*8+j][n=lane&15], C/D col=lane&15 row=quad*4+reg.
// ---------------------------------------------------------------------------
template <bool BIASRELU>
__global__ __launch_bounds__(256, 2) void k_gemm_mfma(
    const _Float16* __restrict__ A, const _Float16* __restrict__ BhT,
    const _Float16* __restrict__ BlT, const float* __restrict__ bias,
    _Float16* __restrict__ C, int M, int N, int K) {
  __shared__ _Float16 Ah[128][40];

  const int tid = threadIdx.x;
  const int bm = blockIdx.x * 128;
  const int bn = blockIdx.y * 128;

  // staging map: thread -> (row, 16-wide k segment)
  const int arow = tid >> 1;
  const int acol = (tid & 1) * 16;
  const bool avalid = (bm + arow) < M;
  const _Float16* aptr = A + (size_t)(bm + arow) * K + acol;

  // wave decomposition
  const int wave = tid >> 6, lane = tid & 63;
  const int wm = (wave & 1) * 64, wn = (wave >> 1) * 64;
  const int lr = lane & 15, quad = lane >> 4;

  const _Float16* bh0 = BhT + (size_t)(bn + wn + lr) * K + quad * 8;
  const _Float16* bl0 = BlT + (size_t)(bn + wn + lr) * K + quad * 8;

  f32x4 acc[4][4] = {};

  for (int k0 = 0; k0 < K; k0 += 32) {
    __syncthreads();
    if (avalid) {
#pragma unroll
      for (int ii = 0; ii < 4; ++ii)
        *(half4v*)&Ah[arow][acol + ii * 4] =
            *(const half4v*)(aptr + k0 + ii * 4);
    } else {
      half4v z = {};
#pragma unroll
      for (int ii = 0; ii < 4; ++ii)
        *(half4v*)&Ah[arow][acol + ii * 4] = z;
    }
    __syncthreads();

    half8v af[4], bhf[4], blf[4];
#pragma unroll
    for (int mi = 0; mi < 4; ++mi)
      af[mi] = *(const half8v*)&Ah[wm + mi * 16 + lr][quad * 8];
#pragma unroll
    for (int ni = 0; ni < 4; ++ni) {
      bhf[ni] = *(const half8v*)(bh0 + (size_t)(ni * 16) * K + k0);
      blf[ni] = *(const half8v*)(bl0 + (size_t)(ni * 16) * K + k0);
    }
#pragma unroll
    for (int mi = 0; mi < 4; ++mi)
#pragma unroll
      for (int ni = 0; ni < 4; ++ni) {
        acc[mi][ni] = __builtin_amdgcn_mfma_f32_16x16x32_f16(
            af[mi], bhf[ni], acc[mi][ni], 0, 0, 0);
        acc[mi][ni] = __builtin_amdgcn_mfma_f32_16x16x32_f16(
            af[mi], blf[ni], acc[mi][ni], 0, 0, 0);
      }
  }

  // epilogue: C/D frag col=lane&15, row=quad*4+r
  float bv[4] = {0.f, 0.f, 0.f, 0.f};
  if (BIASRELU) {
#pragma unroll
    for (int ni = 0; ni < 4; ++ni)
      bv[ni] = bias[bn + wn + ni * 16 + lr];
  }
#pragma unroll
  for (int mi = 0; mi < 4; ++mi)
#pragma unroll
    for (int r = 0; r < 4; ++r) {
      int row = bm + wm + mi * 16 + quad * 4 + r;
      if (row < M) {
#pragma unroll
        for (int ni = 0; ni < 4; ++ni) {
          float v = acc[mi][ni][r];
          if (BIASRELU) v = fmaxf(v + bv[ni], 0.f);
          C[(size_t)row * N + bn + wn + ni * 16 + lr] = (_Float16)v;
        }
      }
    }
}

// ---------------------------------------------------------------------------
// Aggregation: one wave per destination node. lane holds C/64 channels.
// out = di * ( di*h[i] + sum_e dinv[src]*h[src] ) [+ bias] [; relu]
// h gathered as fp16, accumulated fp32.
// ---------------------------------------------------------------------------
template <int C, bool RELU, bool HASBIAS, typename OutT>
__global__ __launch_bounds__(256) void k_agg(const _Float16* __restrict__ h,
                                             const int* __restrict__ esrc,
                                             const int* __restrict__ off,
                                             const float* __restrict__ dinv,
                                             const float* __restrict__ bias,
                                             OutT* __restrict__ out, int n) {
  constexpr int V = C / 64;
  typedef typename vec_t<V>::fv FV;
  typedef typename vec_t<V>::hv HV;
  int gwave = (blockIdx.x * 256 + threadIdx.x) >> 6;
  int lane = threadIdx.x & 63;
  if (gwave >= n) return;
  const int i = gwave;
  const float di = dinv[i];

  FV acc = di * __builtin_convertvector(
                    *(const HV*)(h + (size_t)i * C + lane * V), FV);

  int e = off[i];
  const int e1 = off[i + 1];
  for (; e + 3 < e1; e += 4) {
    int s0 = esrc[e], s1 = esrc[e + 1], s2 = esrc[e + 2], s3 = esrc[e + 3];
    float w0 = dinv[s0], w1 = dinv[s1], w2 = dinv[s2], w3 = dinv[s3];
    HV v0 = *(const HV*)(h + (size_t)s0 * C + lane * V);
    HV v1 = *(const HV*)(h + (size_t)s1 * C + lane * V);
    HV v2 = *(const HV*)(h + (size_t)s2 * C + lane * V);
    HV v3 = *(const HV*)(h + (size_t)s3 * C + lane * V);
    acc += w0 * __builtin_convertvector(v0, FV);
    acc += w1 * __builtin_convertvector(v1, FV);
    acc += w2 * __builtin_convertvector(v2, FV);
    acc += w3 * __builtin_convertvector(v3, FV);
  }
  for (; e < e1; ++e) {
    int s = esrc[e];
    acc += dinv[s] * __builtin_convertvector(
                         *(const HV*)(h + (size_t)s * C + lane * V), FV);
  }

  FV r = acc * di;
  if (HASBIAS) r += *(const FV*)(bias + lane * V);
  if (RELU) {
#pragma unroll
    for (int v = 0; v < V; ++v) r[v] = fmaxf(r[v], 0.f);
  }
  if constexpr (sizeof(OutT) == 2) {
    *(HV*)(out + (size_t)i * C + lane * V) = __builtin_convertvector(r, HV);
  } else {
    *(FV*)(out + (size_t)i * C + lane * V) = r;
  }
}

// ---------------------------------------------------------------------------
extern "C" void kernel_launch(void* const* d_in, const int* in_sizes, int n_in,
                              void* d_out, int out_size, void* d_ws, size_t ws_size,
                              hipStream_t stream) {
  const float* x  = (const float*)d_in[0];
  const int*   ei = (const int*)d_in[1];
  const float* W1 = (const float*)d_in[2];
  const float* b1 = (const float*)d_in[3];
  const float* W2 = (const float*)d_in[4];
  const float* b2 = (const float*)d_in[5];
  float* out = (float*)d_out;

  const int IN_CH = 256, HID = 256, OUT = 128;
  const int N = in_sizes[0] / IN_CH;   // 100000
  const int E = in_sizes[1] / 2;       // 3200000
  const int* src = ei;
  const int* dst = ei + E;
  const int NB = (N + NPB - 1) / NPB;  // 391 buckets

  // workspace layout
  char* p = (char*)d_ws;
  auto alloc = [&](size_t bytes) {
    void* r = (void*)p;
    p += (bytes + 255) & ~(size_t)255;
    return r;
  };
  _Float16* xh   = (_Float16*)alloc((size_t)N * IN_CH * 2);  // later: h1r
  _Float16* xa   = (_Float16*)alloc((size_t)N * IN_CH * 2);  // later: h2
  int*      esrc = (int*)alloc((size_t)E * 4);
  uint2*    tmp  = (uint2*)alloc((size_t)E * 8);
  int*      off  = (int*)alloc((size_t)(N + 1) * 4);
  float*    dinv = (float*)alloc((size_t)N * 4);
  int*      bcnt = (int*)alloc((size_t)(NB + 1) * 4);
  int*      bbase= (int*)alloc((size_t)(NB + 1) * 4);
  int*      gcur = (int*)alloc((size_t)(NB + 1) * 4);
  _Float16* w1h  = (_Float16*)alloc((size_t)IN_CH * HID * 2);
  _Float16* w1l  = (_Float16*)alloc((size_t)IN_CH * HID * 2);
  _Float16* w2h  = (_Float16*)alloc((size_t)HID * OUT * 2);
  _Float16* w2l  = (_Float16*)alloc((size_t)HID * OUT * 2);
  if ((size_t)(p - (char*)d_ws) > ws_size) {
    fprintf(stderr, "kernel_launch: ws too small (need %zu, have %zu)\n",
            (size_t)(p - (char*)d_ws), ws_size);
    return;
  }
  _Float16* h1r = xh;  // xh dead after agg0 (gemm1 reads xa only)
  _Float16* h2  = xa;  // xa dead after gemm1

  const int nBlkP = (E + PCHUNK - 1) / PCHUNK;  // 391

  // --- edge sort ---
  k_zero<<<(NB + 255) / 256, 256, 0, stream>>>(bcnt, NB);
  k_bhist<<<nBlkP, 256, 0, stream>>>(dst, bcnt, E, NB);
  k_bscan<<<1, 512, 0, stream>>>(bcnt, bbase, gcur, NB);
  k_partition<<<nBlkP, 256, 0, stream>>>(src, dst, gcur, tmp, E, NB);
  k_bucket<<<NB, 256, 0, stream>>>(tmp, bbase, off, dinv, esrc, N);
  // --- casts ---
  int n4 = N * IN_CH / 4;
  k_castX<<<(n4 + 255) / 256, 256, 0, stream>>>(x, xh, n4);
  k_castW<<<(256 * 256 + 256 * 128 + 255) / 256, 256, 0, stream>>>(
      W1, W2, w1h, w1l, w2h, w2l);
  // --- layer 1: xa = Â xh ; h1r = relu(xa@W1 + b1) ---
  int aggBlk = (N + 3) / 4;  // 4 waves per block, wave per node
  k_agg<256, false, false, _Float16><<<aggBlk, 256, 0, stream>>>(
      xh, esrc, off, dinv, nullptr, xa, N);
  dim3 g1((N + 127) / 128, HID / 128);
  k_gemm_mfma<true><<<g1, 256, 0, stream>>>(xa, w1h, w1l, b1, h1r, N, HID, IN_CH);
  // --- layer 2: h2 = h1r@W2 ; out = Â h2 + b2 ---
  dim3 g2((N + 127) / 128, OUT / 128);
  k_gemm_mfma<false><<<g2, 256, 0, stream>>>(h1r, w2h, w2l, nullptr, h2, N, OUT, HID);
  k_agg<128, false, true, float><<<aggBlk, 256, 0, stream>>>(
      h2, esrc, off, dinv, b2, out, N);
}